// Round 12
// baseline (181.750 us; speedup 1.0000x reference)
//
#include <hip/hip_runtime.h>
#include <hip/hip_fp16.h>
#include <math.h>

#define H 6
#define D 128
#define K_ALL (H * D)   // 768
#define TSTEPS 24       // K_ALL / 32
#define PADK 776        // 768 + 8 halves pad -> conflict-free fragment reads
#define NPB 8           // nodes per block (1 per wave)

typedef _Float16 f16x8 __attribute__((ext_vector_type(8)));
typedef float f32x4 __attribute__((ext_vector_type(4)));

struct FoldArgs {
    const float* W[4];
    const float* as[4];
    const float* ad[4];
};

// ---------------- CSR build + fused prep ----------------

__global__ __launch_bounds__(256) void zero_kernel(int4* __restrict__ p, int n4) {
    int i = blockIdx.x * 256 + threadIdx.x;
    if (i < n4) p[i] = make_int4(0, 0, 0, 0);
}

// blocks [0, histBlocks): histogram. blocks [histBlocks, +24): wa_all dots.
__global__ __launch_bounds__(256) void hist_prep1_kernel(const int* __restrict__ dst,
                                                         int* __restrict__ deg, int E,
                                                         int histBlocks, FoldArgs fa,
                                                         float* __restrict__ wa_all) {
    int b = blockIdx.x;
    int tid = threadIdx.x;
    if (b < histBlocks) {
        int e = b * 256 + tid;
        if (e < E) atomicAdd(&deg[dst[e]], 1);
    } else {
        int t = (b - histBlocks) * 256 + tid;   // < 6144
        if (t >= 4 * 1536) return;
        int l = t / 1536;
        int r = t % 1536;
        int k = r / 12, j = r % 12;
        int h = (j < 6) ? j : (j - 6);
        const float* att = (j < 6) ? fa.as[l] : fa.ad[l];
        const float* wrow = fa.W[l] + (size_t)k * K_ALL + h * D;
        const float* arow = att + h * D;
        float s = 0.f;
        #pragma unroll 8
        for (int c = 0; c < D; c++) s += wrow[c] * arow[c];
        wa_all[(size_t)l * 1536 + k * 12 + j] = s;
    }
}

// single-pass scan: thread i owns elements [i*16, i*16+16); 2 barriers total.
__global__ __launch_bounds__(1024) void scan_kernel(const int* __restrict__ deg,
                                                    int* __restrict__ rowptr, int n) {
    __shared__ int wsum[16];
    const int tid = threadIdx.x;
    const int lane = tid & 63;
    const int wv = tid >> 6;
    const int base = tid << 4;

    int v[16];
    int tot = 0;
    #pragma unroll
    for (int k = 0; k < 16; k++) {
        int i = base + k;
        int d = (i < n) ? deg[i] : 0;
        v[k] = tot;
        tot += d;
    }
    int s = tot;
    #pragma unroll
    for (int off = 1; off < 64; off <<= 1) {
        int t = __shfl_up(s, off, 64);
        if (lane >= off) s += t;
    }
    if (lane == 63) wsum[wv] = s;
    __syncthreads();
    if (tid < 16) {
        int t = wsum[tid];
        #pragma unroll
        for (int off = 1; off < 16; off <<= 1) {
            int u = __shfl_up(t, off, 64);
            if ((int)tid >= off) t += u;
        }
        wsum[tid] = t;
    }
    __syncthreads();
    int off0 = ((wv > 0) ? wsum[wv - 1] : 0) + s - tot;
    #pragma unroll
    for (int k = 0; k < 16; k++) {
        int i = base + k;
        if (i < n) rowptr[i] = off0 + v[k];
    }
}

// blocks: [0,scat): scatter | +3: waf | +192: bf | +xc: x_in->f16 | +ca: layer-0 a
__global__ __launch_bounds__(256) void scatter_prep2_kernel(const int* __restrict__ src,
                                                            const int* __restrict__ dst,
                                                            int* __restrict__ rowcur,
                                                            int* __restrict__ col, int E,
                                                            int scatBlocks, FoldArgs fa,
                                                            const float* __restrict__ wa_all,
                                                            _Float16* __restrict__ waf,
                                                            _Float16* __restrict__ bf,
                                                            const float* __restrict__ x_in,
                                                            _Float16* __restrict__ xf0,
                                                            float* __restrict__ a0, int N) {
    __shared__ float swa[1536];
    int b = blockIdx.x;
    int tid = threadIdx.x;
    if (b < scatBlocks) {
        int e = b * 256 + tid;
        if (e < E) {
            int p = atomicAdd(&rowcur[dst[e]], 1);
            col[p] = src[e];
        }
        return;
    }
    int bb = b - scatBlocks;
    if (bb < 3) {
        // waf for layer L = bb+1
        int L = bb + 1;
        int lane = tid & 63;
        int t = tid >> 6;
        int j = lane & 15;
        const float* wl = wa_all + (size_t)L * 1536;
        f16x8 v;
        #pragma unroll
        for (int jj = 0; jj < 8; jj++) {
            int k = t * 32 + ((lane >> 4) << 3) + jj;
            float s = (j < 12) ? wl[k * 12 + j] : 0.f;
            v[jj] = (_Float16)s;
        }
        *(f16x8*)(waf + (size_t)bb * 2048 + (size_t)t * 512 + (size_t)lane * 8) = v;
        return;
    }
    bb -= 3;
    if (bb < 192) {
        int idx = bb * 256 + tid;    // < 49152
        int l63 = idx & 63;
        int ct = (idx >> 6) & 7;
        int t = (idx >> 9) % TSTEPS;
        int layer = idx / (TSTEPS * 8 * 64);
        const float* W = fa.W[layer];
        int c = ct * 16 + (l63 & 15);
        f16x8 v;
        #pragma unroll
        for (int j = 0; j < 8; j++) {
            int k = t * 32 + ((l63 >> 4) << 3) + j;
            v[j] = (_Float16)W[(size_t)(k & 127) * K_ALL + ((k >> 7) << 7) + c];
        }
        *(f16x8*)(bf + ((size_t)idx << 3)) = v;
        return;
    }
    bb -= 192;
    int xcBlocks = (N * D / 8 + 255) / 256;
    if (bb < xcBlocks) {
        int idx = bb * 256 + tid;
        if (idx < N * D / 8) {
            const float* s = x_in + (size_t)idx * 8;
            float4 u0 = *(const float4*)s;
            float4 u1 = *(const float4*)(s + 4);
            f16x8 v;
            v[0] = (_Float16)u0.x; v[1] = (_Float16)u0.y;
            v[2] = (_Float16)u0.z; v[3] = (_Float16)u0.w;
            v[4] = (_Float16)u1.x; v[5] = (_Float16)u1.y;
            v[6] = (_Float16)u1.z; v[7] = (_Float16)u1.w;
            *(f16x8*)(xf0 + (size_t)idx * 8) = v;
        }
        return;
    }
    bb -= xcBlocks;
    // layer-0 a: one wave per node (from f32 x_in)
    for (int i = tid; i < 1536; i += 256) swa[i] = wa_all[i];
    __syncthreads();
    int lane = tid & 63;
    int wid = bb * 4 + (tid >> 6);
    if (wid >= N) return;
    float x0 = x_in[(size_t)wid * D + lane];
    float x1 = x_in[(size_t)wid * D + 64 + lane];
    #pragma unroll
    for (int j = 0; j < 12; j++) {
        float p = x0 * swa[lane * 12 + j] + x1 * swa[(64 + lane) * 12 + j];
        #pragma unroll
        for (int off = 32; off; off >>= 1) p += __shfl_xor(p, off, 64);
        if (lane == 0) a0[(size_t)wid * 12 + j] = p;
    }
}

__device__ __forceinline__ float rlf(float v, int j) {
    return __int_as_float(__builtin_amdgcn_readlane(__float_as_int(v), j));
}

// per-wave: aggregate node n (softmax over incoming edges + self loop).
// Gathers f16 x (half the lines of f32); writes f16 plain row into LDS.
__device__ __forceinline__ void aggregate_node(const _Float16* __restrict__ x,
                                               const float* __restrict__ a,
                                               const int* __restrict__ rowend,
                                               const int* __restrict__ deg_,
                                               const int* __restrict__ col,
                                               int n, int lane,
                                               _Float16* __restrict__ xsrow) {
    const int deg = deg_[n];
    const int start = rowend[n] - deg;
    const int nent = deg + 1;

    float adst[H];
    #pragma unroll
    for (int h = 0; h < H; h++) adst[h] = a[(size_t)n * 12 + 6 + h];

    if (nent <= 64) {
        const bool act = lane < nent;
        int s = n;                          // lane 'deg' = self loop
        if (lane < deg) s = col[start + lane];

        const float* as_ = a + (size_t)s * 12;
        float4 v0 = *(const float4*)as_;
        float2 v1 = *(const float2*)(as_ + 4);
        float e0 = v0.x + adst[0], e1 = v0.y + adst[1], e2 = v0.z + adst[2];
        float e3 = v0.w + adst[3], e4 = v1.x + adst[4], e5 = v1.y + adst[5];
        e0 = e0 > 0.f ? e0 : 0.2f * e0;  e1 = e1 > 0.f ? e1 : 0.2f * e1;
        e2 = e2 > 0.f ? e2 : 0.2f * e2;  e3 = e3 > 0.f ? e3 : 0.2f * e3;
        e4 = e4 > 0.f ? e4 : 0.2f * e4;  e5 = e5 > 0.f ? e5 : 0.2f * e5;
        if (!act) { e0 = e1 = e2 = e3 = e4 = e5 = -1e30f; }

        float m0 = e0, m1 = e1, m2 = e2, m3 = e3, m4 = e4, m5 = e5;
        #pragma unroll
        for (int off = 32; off; off >>= 1) {
            m0 = fmaxf(m0, __shfl_xor(m0, off, 64));
            m1 = fmaxf(m1, __shfl_xor(m1, off, 64));
            m2 = fmaxf(m2, __shfl_xor(m2, off, 64));
            m3 = fmaxf(m3, __shfl_xor(m3, off, 64));
            m4 = fmaxf(m4, __shfl_xor(m4, off, 64));
            m5 = fmaxf(m5, __shfl_xor(m5, off, 64));
        }
        float w0 = act ? __expf(e0 - m0) : 0.f;
        float w1 = act ? __expf(e1 - m1) : 0.f;
        float w2 = act ? __expf(e2 - m2) : 0.f;
        float w3 = act ? __expf(e3 - m3) : 0.f;
        float w4 = act ? __expf(e4 - m4) : 0.f;
        float w5 = act ? __expf(e5 - m5) : 0.f;
        float d0 = w0, d1 = w1, d2 = w2, d3 = w3, d4 = w4, d5 = w5;
        #pragma unroll
        for (int off = 32; off; off >>= 1) {
            d0 += __shfl_xor(d0, off, 64);  d1 += __shfl_xor(d1, off, 64);
            d2 += __shfl_xor(d2, off, 64);  d3 += __shfl_xor(d3, off, 64);
            d4 += __shfl_xor(d4, off, 64);  d5 += __shfl_xor(d5, off, 64);
        }
        w0 *= 1.f / (d0 + 1e-16f);  w1 *= 1.f / (d1 + 1e-16f);
        w2 *= 1.f / (d2 + 1e-16f);  w3 *= 1.f / (d3 + 1e-16f);
        w4 *= 1.f / (d4 + 1e-16f);  w5 *= 1.f / (d5 + 1e-16f);

        float a00 = 0, a01 = 0, a02 = 0, a03 = 0, a04 = 0, a05 = 0;
        float a10 = 0, a11 = 0, a12 = 0, a13 = 0, a14 = 0, a15 = 0;
        const _Float16* xb = x + (lane << 1);   // channels c=2*lane, 2*lane+1

        __half2 xa, xbv;
        {
            int s0 = __builtin_amdgcn_readlane(s, 0);
            xa = *(const __half2*)(xb + (size_t)s0 * D);
        }
        xbv = __half2{};
        if (nent > 1) {
            int s1 = __builtin_amdgcn_readlane(s, 1);
            xbv = *(const __half2*)(xb + (size_t)s1 * D);
        }
        for (int j = 0; j < nent; j += 2) {
            __half2 xn0 = __half2{}, xn1 = __half2{};
            if (j + 2 < nent) {
                int s2 = __builtin_amdgcn_readlane(s, j + 2);
                xn0 = *(const __half2*)(xb + (size_t)s2 * D);
            }
            if (j + 3 < nent) {
                int s3 = __builtin_amdgcn_readlane(s, j + 3);
                xn1 = *(const __half2*)(xb + (size_t)s3 * D);
            }
            {
                float2 xf = __half22float2(xa);
                float b0 = rlf(w0, j), b1 = rlf(w1, j), b2 = rlf(w2, j);
                float b3 = rlf(w3, j), b4 = rlf(w4, j), b5 = rlf(w5, j);
                a00 += b0 * xf.x; a10 += b0 * xf.y;
                a01 += b1 * xf.x; a11 += b1 * xf.y;
                a02 += b2 * xf.x; a12 += b2 * xf.y;
                a03 += b3 * xf.x; a13 += b3 * xf.y;
                a04 += b4 * xf.x; a14 += b4 * xf.y;
                a05 += b5 * xf.x; a15 += b5 * xf.y;
            }
            if (j + 1 < nent) {
                float2 xf = __half22float2(xbv);
                float b0 = rlf(w0, j + 1), b1 = rlf(w1, j + 1), b2 = rlf(w2, j + 1);
                float b3 = rlf(w3, j + 1), b4 = rlf(w4, j + 1), b5 = rlf(w5, j + 1);
                a00 += b0 * xf.x; a10 += b0 * xf.y;
                a01 += b1 * xf.x; a11 += b1 * xf.y;
                a02 += b2 * xf.x; a12 += b2 * xf.y;
                a03 += b3 * xf.x; a13 += b3 * xf.y;
                a04 += b4 * xf.x; a14 += b4 * xf.y;
                a05 += b5 * xf.x; a15 += b5 * xf.y;
            }
            xa = xn0; xbv = xn1;
        }
        int c = lane << 1;
        xsrow[0 * D + c] = (_Float16)a00;  xsrow[0 * D + c + 1] = (_Float16)a10;
        xsrow[1 * D + c] = (_Float16)a01;  xsrow[1 * D + c + 1] = (_Float16)a11;
        xsrow[2 * D + c] = (_Float16)a02;  xsrow[2 * D + c + 1] = (_Float16)a12;
        xsrow[3 * D + c] = (_Float16)a03;  xsrow[3 * D + c + 1] = (_Float16)a13;
        xsrow[4 * D + c] = (_Float16)a04;  xsrow[4 * D + c + 1] = (_Float16)a14;
        xsrow[5 * D + c] = (_Float16)a05;  xsrow[5 * D + c + 1] = (_Float16)a15;
    } else {
        // slow fallback (deg >= 64): channels c0=lane, c1=64+lane
        float m[H];
        #pragma unroll
        for (int h = 0; h < H; h++) {
            float e = a[(size_t)n * 12 + h] + adst[h];
            m[h] = (e > 0.f) ? e : 0.2f * e;
        }
        for (int j = 0; j < deg; j++) {
            int s = col[start + j];
            #pragma unroll
            for (int h = 0; h < H; h++) {
                float e = a[(size_t)s * 12 + h] + adst[h];
                e = (e > 0.f) ? e : 0.2f * e;
                m[h] = fmaxf(m[h], e);
            }
        }
        float d[H] = {0, 0, 0, 0, 0, 0};
        float acc0[H] = {0, 0, 0, 0, 0, 0};
        float acc1[H] = {0, 0, 0, 0, 0, 0};
        int c0 = lane, c1 = 64 + lane;
        for (int j = 0; j <= deg; j++) {
            int s = (j < deg) ? col[start + j] : n;
            float w[H];
            #pragma unroll
            for (int h = 0; h < H; h++) {
                float e = a[(size_t)s * 12 + h] + adst[h];
                e = (e > 0.f) ? e : 0.2f * e;
                w[h] = __expf(e - m[h]);
                d[h] += w[h];
            }
            float xv0 = (float)x[(size_t)s * D + c0];
            float xv1 = (float)x[(size_t)s * D + c1];
            #pragma unroll
            for (int h = 0; h < H; h++) {
                acc0[h] += w[h] * xv0;
                acc1[h] += w[h] * xv1;
            }
        }
        #pragma unroll
        for (int h = 0; h < H; h++) {
            float inv = 1.0f / (d[h] + 1e-16f);
            xsrow[h * D + c0] = (_Float16)(acc0[h] * inv);
            xsrow[h * D + c1] = (_Float16)(acc1[h] * inv);
        }
    }
}

// ---------------- fused layer: aggregate(8 nodes -> LDS) + MFMA GEMM + a ----------------
__global__ __launch_bounds__(512) void layer_kernel(const _Float16* __restrict__ x16,
                                                    const float* __restrict__ a_in,
                                                    const int* __restrict__ rowend,
                                                    const int* __restrict__ deg_,
                                                    const int* __restrict__ col,
                                                    const _Float16* __restrict__ bf,
                                                    const float* __restrict__ bias,
                                                    float* __restrict__ xout_f32,
                                                    _Float16* __restrict__ xf16o,
                                                    const _Float16* __restrict__ awf,
                                                    float* __restrict__ a_out, int M) {
    __shared__ _Float16 xs16[16][PADK];   // rows 0..7 aggregated; 8..15 garbage
    __shared__ _Float16 xso[16][136];     // output rows (f16) for fused a
    const int wave = (int)(threadIdx.x >> 6);
    const int lane = (int)(threadIdx.x & 63);
    const int m0 = (int)(blockIdx.x << 3);

    // phase 1: each wave aggregates 1 node
    {
        int n = m0 + wave;
        if (n < M)
            aggregate_node(x16, a_in, rowend, deg_, col, n, lane, &xs16[wave][0]);
    }
    __syncthreads();

    // phase 2: GEMM — wave w owns col-tile w (cols w*16..w*16+15)
    f32x4 acc = {0.f, 0.f, 0.f, 0.f};
    const _Float16* ars = &xs16[lane & 15][(lane >> 4) << 3];
    const _Float16* bp = bf + (size_t)wave * 512 + (size_t)lane * 8;
    for (int t = 0; t < TSTEPS; t++) {
        f16x8 av = *(const f16x8*)(ars + t * 32);
        f16x8 bv = *(const f16x8*)(bp + (size_t)t * 4096);
        acc = __builtin_amdgcn_mfma_f32_16x16x32_f16(av, bv, acc, 0, 0, 0);
    }

    const float inv6 = 1.0f / 6.0f;
    const int cl = lane & 15;
    const int ccol = wave * 16 + cl;
    const int r0 = (lane >> 4) << 2;
    const float bs = bias[ccol];
    #pragma unroll
    for (int reg = 0; reg < 4; reg++) {
        int ml = r0 + reg;
        int m = m0 + ml;
        float v = acc[reg] * inv6 + bs;
        v = v > 0.f ? v : 0.f;
        _Float16 vh = (_Float16)v;
        if (ml < NPB && m < M) {
            if (xout_f32) xout_f32[(size_t)m * D + ccol] = v;
            if (xf16o) xf16o[(size_t)m * D + ccol] = vh;
        }
        xso[ml][ccol] = vh;
    }

    // phase 3: fused next-layer attention logits (wave 0)
    if (awf) {
        __syncthreads();
        if (wave == 0) {
            f32x4 ac = {0.f, 0.f, 0.f, 0.f};
            #pragma unroll
            for (int t = 0; t < 4; t++) {
                f16x8 av = *(const f16x8*)&xso[cl][t * 32 + ((lane >> 4) << 3)];
                f16x8 bv = *(const f16x8*)(awf + (size_t)t * 512 + (size_t)lane * 8);
                ac = __builtin_amdgcn_mfma_f32_16x16x32_f16(av, bv, ac, 0, 0, 0);
            }
            if (cl < 12) {
                #pragma unroll
                for (int reg = 0; reg < 4; reg++) {
                    int ml = r0 + reg;
                    int m = m0 + ml;
                    if (ml < NPB && m < M) a_out[(size_t)m * 12 + cl] = ac[reg];
                }
            }
        }
    }
}

// ---------------- host ----------------

extern "C" void kernel_launch(void* const* d_in, const int* in_sizes, int n_in,
                              void* d_out, int out_size, void* d_ws, size_t ws_size,
                              hipStream_t stream) {
    const float* x_in = (const float*)d_in[0];
    const int* ei = (const int*)d_in[1];
    int N = in_sizes[0] / D;
    int E = in_sizes[1] / 2;
    const int* srcp = ei;
    const int* dstp = ei + E;

    size_t bf_halves_per_layer = (size_t)TSTEPS * 8 * 512;   // 98304

    float* ws = (float*)d_ws;
    float* abuf0 = ws;
    float* abuf1 = abuf0 + (size_t)N * 12;
    float* wa_all = abuf1 + (size_t)N * 12;          // 4*1536 floats
    _Float16* waf = (_Float16*)(wa_all + 4 * 1536);  // 3 layers x 2048 halves
    _Float16* w16f = waf + 3 * 2048;
    _Float16* xf0 = w16f + 4 * bf_halves_per_layer;
    _Float16* xfA = xf0 + (size_t)N * D;
    _Float16* xfB = xfA + (size_t)N * D;
    int* deg = (int*)(xfB + (size_t)N * D);
    int* rowptr = deg + N;
    int* col = rowptr + (N + 1);

    FoldArgs fa;
    for (int l = 0; l < 4; l++) {
        fa.W[l]  = (const float*)d_in[2 + 4 * l];
        fa.as[l] = (const float*)d_in[3 + 4 * l];
        fa.ad[l] = (const float*)d_in[4 + 4 * l];
    }

    // CSR build + fused prep
    int n4 = (N + 3) / 4;
    zero_kernel<<<(n4 + 255) / 256, 256, 0, stream>>>((int4*)deg, n4);
    int histBlocks = (E + 255) / 256;
    hist_prep1_kernel<<<histBlocks + 24, 256, 0, stream>>>(dstp, deg, E, histBlocks, fa, wa_all);
    scan_kernel<<<1, 1024, 0, stream>>>(deg, rowptr, N);
    int scatBlocks = (E + 255) / 256;
    int xcBlocks = (N * D / 8 + 255) / 256;
    int caBlocks = (N + 3) / 4;
    scatter_prep2_kernel<<<scatBlocks + 3 + 192 + xcBlocks + caBlocks, 256, 0, stream>>>(
        srcp, dstp, rowptr, col, E, scatBlocks, fa, wa_all, waf, w16f, x_in, xf0, abuf0, N);

    const _Float16* xcur = xf0;
    float* acur = abuf0;
    float* anext = abuf1;
    for (int l = 0; l < 4; l++) {
        const float* b = (const float*)d_in[5 + 4 * l];
        float* xoutf = (l == 3) ? (float*)d_out : nullptr;
        _Float16* xf16o = (l == 3) ? nullptr : ((l & 1) ? xfB : xfA);
        const _Float16* awf = (l < 3) ? (waf + (size_t)l * 2048) : (const _Float16*)nullptr;

        layer_kernel<<<(N + NPB - 1) / NPB, 512, 0, stream>>>(xcur, acur, rowptr, deg, col,
                                                              w16f + (size_t)l * bf_halves_per_layer,
                                                              b, xoutf, xf16o, awf, anext, N);
        xcur = xf16o;
        float* tmp = acur; acur = anext; anext = tmp;
    }
}